// Round 8
// baseline (646.365 us; speedup 1.0000x reference)
//
#include <hip/hip_runtime.h>

typedef unsigned short u16;
typedef unsigned int   uint;
typedef __attribute__((ext_vector_type(8))) short bf16x8;
typedef __attribute__((ext_vector_type(4))) float f32x4;
typedef __attribute__((ext_vector_type(16))) float f32x16;

constexpr int NELEM = 100;
constexpr int EMBED = 256;
constexpr int HID   = 512;
constexpr int KX    = 306;     // EMBED + 50
constexpr int G     = 50;
constexpr int M     = 64;      // edges per block
constexpr int THREADS = 512;   // 8 waves
constexpr int HSTR  = 540;     // hbuf row stride (bf16): bank-stride 14 ⇒ ~conflict-free

// frag-ready weight buffers in d_ws (bf16), 32x32x16 operand layout
// (row/col = lane&31, k = (lane>>5)*8 + j):
//  Wb : [20 ks2][16 nt][64 lane][8]   (k==306 row carries b_in; >306 zero)
//  Gb : [ 4 ks2][16 nt][64 lane][8]   (gk>=50 zero)
//  Ob : [16 ks ][64 lane][8]          (16x16x32 layout, unchanged)
//  Eb : emb_table converted to bf16 (optional, if ws fits)
constexpr int WB_ELEMS = 20 * 16 * 64 * 8;
constexpr int GB_ELEMS = 4 * 16 * 64 * 8;
constexpr int OB_ELEMS = 16 * 64 * 8;

__device__ __forceinline__ u16 f2bf(float x) {
    uint u = __float_as_uint(x);
    u = (u + 0x7fffu + ((u >> 16) & 1u)) >> 16;
    return (u16)u;
}
__device__ __forceinline__ uint pk2(float a, float b) {
    return (uint)f2bf(a) | ((uint)f2bf(b) << 16);
}
__device__ __forceinline__ float bflo(uint u) { return __uint_as_float(u << 16); }
__device__ __forceinline__ float bfhi(uint u) { return __uint_as_float(u & 0xffff0000u); }
__device__ __forceinline__ f32x4 mfma16(bf16x8 a, bf16x8 b, f32x4 c) {
    return __builtin_amdgcn_mfma_f32_16x16x32_bf16(a, b, c, 0, 0, 0);
}
__device__ __forceinline__ f32x16 mfma32(bf16x8 a, bf16x8 b, f32x16 c) {
    return __builtin_amdgcn_mfma_f32_32x32x16_bf16(a, b, c, 0, 0, 0);
}
__device__ __forceinline__ void load_lds16(const u16* g, u16* l) {
    __builtin_amdgcn_global_load_lds(
        (const __attribute__((address_space(1))) uint*)g,
        (__attribute__((address_space(3))) uint*)l, 16, 0, 0);
}

// ---- prep: weights -> fragment-ready bf16 layouts --------------------------
__global__ void prep_kernel(const float* __restrict__ W_in,   // [512][306]
                            const float* __restrict__ gate_W, // [512][50]
                            const float* __restrict__ W_out,  // [8][512]
                            const float* __restrict__ b_in,   // [512]
                            u16* __restrict__ Wb,
                            u16* __restrict__ Gb,
                            u16* __restrict__ Ob) {
    int idx = blockIdx.x * 256 + threadIdx.x;
    if (idx < WB_ELEMS) {
        int j = idx & 7, lane = (idx >> 3) & 63, nt = (idx >> 9) & 15, ks2 = idx >> 13;
        int h = nt * 32 + (lane & 31);
        int k = ks2 * 16 + (lane >> 5) * 8 + j;
        float v = (k < KX) ? W_in[h * KX + k] : ((k == KX) ? b_in[h] : 0.f);
        Wb[idx] = f2bf(v);
    } else if (idx < WB_ELEMS + GB_ELEMS) {
        int i2 = idx - WB_ELEMS;
        int j = i2 & 7, lane = (i2 >> 3) & 63, nt = (i2 >> 9) & 15, ks2 = i2 >> 13;
        int h = nt * 32 + (lane & 31);
        int gk = ks2 * 16 + (lane >> 5) * 8 + j;
        Gb[i2] = f2bf((gk < G) ? gate_W[h * G + gk] : 0.f);
    } else if (idx < WB_ELEMS + GB_ELEMS + OB_ELEMS) {
        int i2 = idx - WB_ELEMS - GB_ELEMS;
        int j = i2 & 7, lane = (i2 >> 3) & 63, ks = i2 >> 9;
        int n = lane & 15;
        int k = ks * 32 + (lane >> 4) * 8 + j;
        Ob[i2] = f2bf((n < 8) ? W_out[n * HID + k] : 0.f);
    }
}

// ---- prep: emb_table f32 -> bf16 ------------------------------------------
__global__ void conv_table_kernel(const float* __restrict__ src,
                                  uint* __restrict__ dst, int npairs) {
    int i = blockIdx.x * 256 + threadIdx.x;
    if (i < npairs) {
        float2 v = ((const float2*)src)[i];
        dst[i] = pk2(v.x, v.y);
    }
}

// ---- fused main kernel -----------------------------------------------------
template <bool BF16_TABLE>
__global__ __launch_bounds__(THREADS, 4)
void pair_embed_kernel(const int* __restrict__ anum,
                       const int* __restrict__ edge_index,
                       const int* __restrict__ edge_to_src,
                       const float* __restrict__ dist,
                       const float* __restrict__ emb_table,
                       const u16* __restrict__ Eb,
                       const float* __restrict__ b_out,
                       const u16* __restrict__ Wb,
                       const u16* __restrict__ Gb,
                       const u16* __restrict__ Ob,
                       float* __restrict__ out,
                       int E) {
    // union: afrag [20 ks2][2 mt][64 lane][8] = 40 KB during GEMM,
    // then hbuf [64 e][540] bf16 = 69.1 KB for the out-projection.
    __shared__ __align__(16) u16 smem[M * HSTR];
    __shared__ float red[8][64][4];     // out-proj partials (k-split)
    __shared__ int   rowbase[M];
    __shared__ float dste[M];
    u16* afrag = smem;
    u16* hbuf  = smem;

    const int t  = threadIdx.x;
    const int e0 = blockIdx.x * M;
    const int wave = t >> 6, lane = t & 63;

    if (t < M) {
        int eg = e0 + t;
        int pair = 0; float d = 0.f;
        if (eg < E) {
            int src = edge_to_src[eg];
            pair = anum[edge_index[src]] + NELEM * anum[edge_index[E + src]];
            d = dist[eg];
        }
        rowbase[t] = pair * EMBED;
        dste[t]    = d;
    }
    __syncthreads();

    // ---- stage A-tile -----------------------------------------------------
    // chunk cix = p*512 + t  ->  afrag[cix*8..], with ks2 = p*4 + (wave>>1),
    // mt = wave&1 (both wave-uniform), edge row = mt*32 + (lane&31),
    // k-chunk = (lane>>5)*8. LDS dest = uniform base + lane*16B (DMA-legal).
    {
        const int row = (wave & 1) * 32 + (lane & 31);
        const int sub = lane >> 5;
        const int rb  = rowbase[row];
        if (BF16_TABLE) {
            const u16* gsrc = Eb + rb + sub * 8;
            #pragma unroll
            for (int p = 0; p < 4; ++p) {
                int ks2 = p * 4 + (wave >> 1);
                load_lds16(gsrc + ks2 * 16, &afrag[(p * 512 + t) * 8]);
            }
        } else {
            #pragma unroll 1
            for (int p = 0; p < 4; ++p) {
                int ks2 = p * 4 + (wave >> 1);
                const float4* src = (const float4*)(emb_table + rb + ks2 * 16 + sub * 8);
                float4 v0 = src[0], v1 = src[1];
                uint4 w;
                w.x = pk2(v0.x, v0.y); w.y = pk2(v0.z, v0.w);
                w.z = pk2(v1.x, v1.y); w.w = pk2(v1.z, v1.w);
                *(uint4*)&afrag[(p * 512 + t) * 8] = w;
            }
        }
        // rbf + bias chunk (ks2 16..19): k in [256, 320)
        {
            const float sp    = 12.0f / 49.0f;
            const float coeff = -0.5f / (sp * sp);
            float d  = dste[row];
            int   k0 = (16 + (wave >> 1)) * 16 + sub * 8;
            float f[8];
            #pragma unroll
            for (int j = 0; j < 8; ++j) {
                int k = k0 + j;
                float dd = d - sp * (float)(k - EMBED);
                f[j] = (k < KX) ? __expf(coeff * dd * dd) : ((k == KX) ? 1.f : 0.f);
            }
            uint4 w;
            w.x = pk2(f[0], f[1]); w.y = pk2(f[2], f[3]);
            w.z = pk2(f[4], f[5]); w.w = pk2(f[6], f[7]);
            *(uint4*)&afrag[(4 * 512 + t) * 8] = w;
        }
    }
    __syncthreads();

    const f32x16 z16 = {0.f,0.f,0.f,0.f,0.f,0.f,0.f,0.f,
                        0.f,0.f,0.f,0.f,0.f,0.f,0.f,0.f};

    // ---- gate GEMM first (shares a-frags ks2 16..19), pack to bf16 ---------
    uint gp[2][2][8];    // [ntl][mt][q] packed gate values
    {
        f32x16 gacc[2][2];
        gacc[0][0] = z16; gacc[0][1] = z16; gacc[1][0] = z16; gacc[1][1] = z16;
        #pragma unroll
        for (int kg = 0; kg < 4; ++kg) {
            bf16x8 a0 = *(const bf16x8*)&afrag[(((16 + kg) * 2 + 0) * 64 + lane) * 8];
            bf16x8 a1 = *(const bf16x8*)&afrag[(((16 + kg) * 2 + 1) * 64 + lane) * 8];
            #pragma unroll
            for (int ntl = 0; ntl < 2; ++ntl) {
                bf16x8 w = *(const bf16x8*)&Gb[((kg * 16 + wave * 2 + ntl) * 64 + lane) * 8];
                gacc[ntl][0] = mfma32(w, a0, gacc[ntl][0]);
                gacc[ntl][1] = mfma32(w, a1, gacc[ntl][1]);
            }
        }
        #pragma unroll
        for (int ntl = 0; ntl < 2; ++ntl)
            #pragma unroll
            for (int mt = 0; mt < 2; ++mt)
                #pragma unroll
                for (int q = 0; q < 8; ++q)
                    gp[ntl][mt][q] = pk2(gacc[ntl][mt][2*q], gacc[ntl][mt][2*q+1]);
    }

    // ---- main GEMM: 20 ks2, B loaded once per block ------------------------
    f32x16 acc[2][2];
    acc[0][0] = z16; acc[0][1] = z16; acc[1][0] = z16; acc[1][1] = z16;
    #pragma unroll 2
    for (int ks2 = 0; ks2 < 20; ++ks2) {
        bf16x8 a0 = *(const bf16x8*)&afrag[((ks2 * 2 + 0) * 64 + lane) * 8];
        bf16x8 a1 = *(const bf16x8*)&afrag[((ks2 * 2 + 1) * 64 + lane) * 8];
        #pragma unroll
        for (int ntl = 0; ntl < 2; ++ntl) {
            bf16x8 w = *(const bf16x8*)&Wb[((ks2 * 16 + wave * 2 + ntl) * 64 + lane) * 8];
            acc[ntl][0] = mfma32(w, a0, acc[ntl][0]);
            acc[ntl][1] = mfma32(w, a1, acc[ntl][1]);
        }
    }

    // ---- h = silu(pre) * gate -> packed regs -------------------------------
    uint hpack[2][2][8];
    #pragma unroll
    for (int ntl = 0; ntl < 2; ++ntl) {
        #pragma unroll
        for (int mt = 0; mt < 2; ++mt) {
            #pragma unroll
            for (int q = 0; q < 8; ++q) {
                float p0 = acc[ntl][mt][2*q];
                float p1 = acc[ntl][mt][2*q+1];
                float s0 = p0 / (1.f + __expf(-p0));
                float s1 = p1 / (1.f + __expf(-p1));
                hpack[ntl][mt][q] = pk2(s0 * bflo(gp[ntl][mt][q]),
                                        s1 * bfhi(gp[ntl][mt][q]));
            }
        }
    }
    __syncthreads();   // all afrag reads complete; smem becomes hbuf

    // ---- h-writes: D rows = (r&3) + 8*(r>>2) + 4*(lane>>5), col = edge -----
    #pragma unroll
    for (int ntl = 0; ntl < 2; ++ntl) {
        #pragma unroll
        for (int mt = 0; mt < 2; ++mt) {
            int e = mt * 32 + (lane & 31);
            #pragma unroll
            for (int c = 0; c < 4; ++c) {
                int h0 = (wave * 2 + ntl) * 32 + c * 8 + (lane >> 5) * 4;
                *(uint2*)&hbuf[e * HSTR + h0] =
                    make_uint2(hpack[ntl][mt][c*2], hpack[ntl][mt][c*2+1]);
            }
        }
    }
    __syncthreads();

    // ---- out-proj: 16x16x32, 8-wave split (4 m-tiles x 2 k-halves) ---------
    {
        const int col = lane & 15, quad = lane >> 4;
        const int mt4 = wave & 3, kh = wave >> 2;
        f32x4 oacc = {0.f, 0.f, 0.f, 0.f};
        #pragma unroll
        for (int kk = 0; kk < 8; ++kk) {
            int ks = kh * 8 + kk;
            bf16x8 a = *(const bf16x8*)&hbuf[(mt4 * 16 + col) * HSTR + ks * 32 + quad * 8];
            bf16x8 b = *(const bf16x8*)&Ob[(ks * 64 + lane) * 8];
            oacc = mfma16(a, b, oacc);
        }
        *(float4*)&red[wave][lane][0] = *(float4*)&oacc;
    }
    __syncthreads();

    // ---- final reduce (k-halves) + write ----------------------------------
    if (t < 256) {
        const int mt = t >> 6, l = t & 63;
        const int c  = l & 15;
        float4 s;
        s.x = red[mt][l][0] + red[mt + 4][l][0];
        s.y = red[mt][l][1] + red[mt + 4][l][1];
        s.z = red[mt][l][2] + red[mt + 4][l][2];
        s.w = red[mt][l][3] + red[mt + 4][l][3];
        if (c < 8) {
            int eg0 = e0 + mt * 16 + (l >> 4) * 4;
            float bo = b_out[c];
            if (eg0 + 3 < E) {
                float4 v = make_float4(s.x + bo, s.y + bo, s.z + bo, s.w + bo);
                *(float4*)&out[c * E + eg0] = v;
            } else {
                float sv[4] = {s.x, s.y, s.z, s.w};
                #pragma unroll
                for (int r = 0; r < 4; ++r)
                    if (eg0 + r < E) out[c * E + eg0 + r] = sv[r] + bo;
            }
        }
    }
}

extern "C" void kernel_launch(void* const* d_in, const int* in_sizes, int n_in,
                              void* d_out, int out_size, void* d_ws, size_t ws_size,
                              hipStream_t stream) {
    const int*   anum        = (const int*)d_in[0];
    const int*   edge_index  = (const int*)d_in[1];
    const int*   edge_to_src = (const int*)d_in[2];
    const float* dist        = (const float*)d_in[3];
    const float* emb_table   = (const float*)d_in[4];
    const float* gate_W      = (const float*)d_in[5];
    const float* W_in        = (const float*)d_in[6];
    const float* b_in        = (const float*)d_in[7];
    const float* W_out       = (const float*)d_in[8];
    const float* b_out       = (const float*)d_in[9];
    const int E   = in_sizes[3];
    const int TBL = in_sizes[4];               // NELEM^2 * EMBED elements

    u16* Wb = (u16*)d_ws;
    u16* Gb = Wb + WB_ELEMS;
    u16* Ob = Gb + GB_ELEMS;
    u16* Eb = Ob + OB_ELEMS;

    const size_t need_bf16 = (size_t)(WB_ELEMS + GB_ELEMS + OB_ELEMS + TBL) * sizeof(u16);
    const bool use_bf16_table = ws_size >= need_bf16;

    int total = WB_ELEMS + GB_ELEMS + OB_ELEMS;
    prep_kernel<<<(total + 255) / 256, 256, 0, stream>>>(
        W_in, gate_W, W_out, b_in, Wb, Gb, Ob);

    const int nblocks = (E + M - 1) / M;
    if (use_bf16_table) {
        int npairs = TBL / 2;
        conv_table_kernel<<<(npairs + 255) / 256, 256, 0, stream>>>(
            emb_table, (uint*)Eb, npairs);
        pair_embed_kernel<true><<<nblocks, THREADS, 0, stream>>>(
            anum, edge_index, edge_to_src, dist, emb_table, Eb,
            b_out, Wb, Gb, Ob, (float*)d_out, E);
    } else {
        pair_embed_kernel<false><<<nblocks, THREADS, 0, stream>>>(
            anum, edge_index, edge_to_src, dist, emb_table, Eb,
            b_out, Wb, Gb, Ob, (float*)d_out, E);
    }
}

// Round 10
// 312.024 us; speedup vs baseline: 2.0715x; 2.0715x over previous
//
#include <hip/hip_runtime.h>

typedef unsigned short u16;
typedef unsigned int   uint;
typedef __attribute__((ext_vector_type(8))) short bf16x8;
typedef __attribute__((ext_vector_type(4))) float f32x4;

constexpr int NELEM = 100;
constexpr int EMBED = 256;
constexpr int HID   = 512;
constexpr int KX    = 306;     // EMBED + 50
constexpr int G     = 50;
constexpr int M     = 64;      // edges per block
constexpr int THREADS = 512;   // 8 waves

// frag-ready weight buffers in d_ws (bf16):
//  Wb : [10 ks][32 nt][64 lane][8]   (k==306 row carries b_in; >306 zero)
//  Gb : [ 2 ks][32 nt][64 lane][8]   (g>=50 zero)
//  Ob : [16 slice][64 lane][8]       permuted W_out for in-register out-proj:
//        slice s covers hid block s*32; element (lane,j) = W_out[lane&15]
//        [s*32 + (j>>2)*16 + (lane>>4)*4 + (j&3)]  (0 for lane&15 >= 8)
//  Eb : emb_table converted to bf16 (optional, if ws fits)
constexpr int WB_ELEMS = 10 * 32 * 64 * 8;
constexpr int GB_ELEMS = 2 * 32 * 64 * 8;
constexpr int OB_ELEMS = 16 * 64 * 8;

__device__ __forceinline__ u16 f2bf(float x) {
    uint u = __float_as_uint(x);
    u = (u + 0x7fffu + ((u >> 16) & 1u)) >> 16;
    return (u16)u;
}
__device__ __forceinline__ uint pk2(float a, float b) {
    return (uint)f2bf(a) | ((uint)f2bf(b) << 16);
}
__device__ __forceinline__ float bflo(uint u) { return __uint_as_float(u << 16); }
__device__ __forceinline__ float bfhi(uint u) { return __uint_as_float(u & 0xffff0000u); }
__device__ __forceinline__ float silu(float p) { return p / (1.f + __expf(-p)); }
__device__ __forceinline__ f32x4 mfma16(bf16x8 a, bf16x8 b, f32x4 c) {
    return __builtin_amdgcn_mfma_f32_16x16x32_bf16(a, b, c, 0, 0, 0);
}
__device__ __forceinline__ void load_lds16(const u16* g, u16* l) {
    __builtin_amdgcn_global_load_lds(
        (const __attribute__((address_space(1))) uint*)g,
        (__attribute__((address_space(3))) uint*)l, 16, 0, 0);
}

// ---- prep: weights -> fragment-ready bf16 layouts --------------------------
__global__ void prep_kernel(const float* __restrict__ W_in,   // [512][306]
                            const float* __restrict__ gate_W, // [512][50]
                            const float* __restrict__ W_out,  // [8][512]
                            const float* __restrict__ b_in,   // [512]
                            u16* __restrict__ Wb,
                            u16* __restrict__ Gb,
                            u16* __restrict__ Ob) {
    int idx = blockIdx.x * 256 + threadIdx.x;
    if (idx < WB_ELEMS) {
        int j = idx & 7, lane = (idx >> 3) & 63, nt = (idx >> 9) & 31, ks = idx >> 14;
        int h = nt * 16 + (lane & 15);
        int k = ks * 32 + (lane >> 4) * 8 + j;
        float v = (k < KX) ? W_in[h * KX + k] : ((k == KX) ? b_in[h] : 0.f);
        Wb[idx] = f2bf(v);
    } else if (idx < WB_ELEMS + GB_ELEMS) {
        int i2 = idx - WB_ELEMS;
        int j = i2 & 7, lane = (i2 >> 3) & 63, nt = (i2 >> 9) & 31, ks = i2 >> 14;
        int h = nt * 16 + (lane & 15);
        int g = ks * 32 + (lane >> 4) * 8 + j;
        Gb[i2] = f2bf((g < G) ? gate_W[h * G + g] : 0.f);
    } else if (idx < WB_ELEMS + GB_ELEMS + OB_ELEMS) {
        int i2 = idx - WB_ELEMS - GB_ELEMS;
        int j = i2 & 7, lane = (i2 >> 3) & 63, s = i2 >> 9;
        int m = lane & 15, q = lane >> 4;
        int hid = s * 32 + (j >> 2) * 16 + q * 4 + (j & 3);
        Ob[i2] = f2bf((m < 8) ? W_out[m * HID + hid] : 0.f);
    }
}

// ---- prep: emb_table f32 -> bf16 ------------------------------------------
__global__ void conv_table_kernel(const float* __restrict__ src,
                                  uint* __restrict__ dst, int npairs) {
    int i = blockIdx.x * 256 + threadIdx.x;
    if (i < npairs) {
        float2 v = ((const float2*)src)[i];
        dst[i] = pk2(v.x, v.y);
    }
}

// ---- fused main kernel -----------------------------------------------------
template <bool BF16_TABLE>
__global__ __launch_bounds__(THREADS, 4)
void pair_embed_kernel(const int* __restrict__ anum,
                       const int* __restrict__ edge_index,
                       const int* __restrict__ edge_to_src,
                       const float* __restrict__ dist,
                       const float* __restrict__ emb_table,
                       const u16* __restrict__ Eb,
                       const float* __restrict__ b_out,
                       const u16* __restrict__ Wb,
                       const u16* __restrict__ Gb,
                       const u16* __restrict__ Ob,
                       float* __restrict__ out,
                       int E) {
    // afrag [10 ks][4 mt][64 lane][8] = 40 KB; red (32 KB) unions into it.
    __shared__ __align__(16) u16 smem[10 * 4 * 64 * 8];
    __shared__ int   rowbase[M];
    __shared__ float dste[M];
    u16*   afrag = smem;
    float* redf  = (float*)smem;     // [8 wave][4 mt][64 lane][4]

    const int t  = threadIdx.x;
    const int e0 = blockIdx.x * M;
    const int wave = t >> 6, lane = t & 63;
    const int col = lane & 15, quad = lane >> 4;

    if (t < M) {
        int eg = e0 + t;
        int pair = 0; float d = 0.f;
        if (eg < E) {
            int src = edge_to_src[eg];
            pair = anum[edge_index[src]] + NELEM * anum[edge_index[E + src]];
            d = dist[eg];
        }
        rowbase[t] = pair * EMBED;
        dste[t]    = d;
    }
    __syncthreads();

    // ---- stage A-tile -----------------------------------------------------
    // emb chunks: wave w handles ks=w (k = w*32), mt 0..3. Lane (q,c) loads
    // 16B at row (mt*16+c), k-offset q*8. LDS dest = chunk base + lane*16B.
    {
        if (BF16_TABLE) {
            #pragma unroll
            for (int mt = 0; mt < 4; ++mt) {
                int rb = rowbase[mt * 16 + col];
                const u16* g = Eb + rb + wave * 32 + quad * 8;
                load_lds16(g, &afrag[((wave * 4 + mt) * 64 + lane) * 8]);
            }
        } else {
            #pragma unroll 1
            for (int mt = 0; mt < 4; ++mt) {
                int rb = rowbase[mt * 16 + col];
                const float4* src = (const float4*)(emb_table + rb + wave * 32 + quad * 8);
                float4 v0 = src[0], v1 = src[1];
                uint4 w;
                w.x = pk2(v0.x, v0.y); w.y = pk2(v0.z, v0.w);
                w.z = pk2(v1.x, v1.y); w.w = pk2(v1.z, v1.w);
                *(uint4*)&afrag[((wave * 4 + mt) * 64 + lane) * 8] = w;
            }
        }
        // rbf + bias chunk: one per wave: ks = 8+(wave&1), mt = wave>>1
        {
            const float sp    = 12.0f / 49.0f;
            const float coeff = -0.5f / (sp * sp);
            int ksr = 8 + (wave & 1), mtr = wave >> 1;
            float d  = dste[mtr * 16 + col];
            int   k0 = ksr * 32 + quad * 8;
            float f[8];
            #pragma unroll
            for (int j = 0; j < 8; ++j) {
                int k = k0 + j;
                int g = k - EMBED;
                float dd = d - sp * (float)g;
                f[j] = (g < G) ? __expf(coeff * dd * dd) : ((k == KX) ? 1.f : 0.f);
            }
            uint4 w;
            w.x = pk2(f[0], f[1]); w.y = pk2(f[2], f[3]);
            w.z = pk2(f[4], f[5]); w.w = pk2(f[6], f[7]);
            *(uint4*)&afrag[((ksr * 4 + mtr) * 64 + lane) * 8] = w;
        }
    }
    __syncthreads();

    const f32x4 z4 = {0.f, 0.f, 0.f, 0.f};
    f32x4 oacc[4] = {z4, z4, z4, z4};        // out-proj partials, D[head][edge]

    #pragma unroll
    for (int nh = 0; nh < 2; ++nh) {
        // ---- gate GEMM (ks 8..9), pack to bf16 (gp: 16 VGPR) ---------------
        uint gp[2][4][2];
        {
            f32x4 gacc[2][4];
            #pragma unroll
            for (int ntl = 0; ntl < 2; ++ntl)
                #pragma unroll
                for (int mt = 0; mt < 4; ++mt) gacc[ntl][mt] = z4;
            #pragma unroll
            for (int ks = 0; ks < 2; ++ks) {
                bf16x8 a[4];
                #pragma unroll
                for (int mt = 0; mt < 4; ++mt)
                    a[mt] = *(const bf16x8*)&afrag[(((8 + ks) * 4 + mt) * 64 + lane) * 8];
                #pragma unroll
                for (int ntl = 0; ntl < 2; ++ntl) {
                    int ntg = wave * 4 + nh * 2 + ntl;
                    bf16x8 g = *(const bf16x8*)&Gb[((ks * 32 + ntg) * 64 + lane) * 8];
                    #pragma unroll
                    for (int mt = 0; mt < 4; ++mt)
                        gacc[ntl][mt] = mfma16(g, a[mt], gacc[ntl][mt]);   // A=W, B=x
                }
            }
            #pragma unroll
            for (int ntl = 0; ntl < 2; ++ntl)
                #pragma unroll
                for (int mt = 0; mt < 4; ++mt) {
                    gp[ntl][mt][0] = pk2(gacc[ntl][mt][0], gacc[ntl][mt][1]);
                    gp[ntl][mt][1] = pk2(gacc[ntl][mt][2], gacc[ntl][mt][3]);
                }
        }

        // ---- main GEMM (ks 0..9, bias folded at k=306) ---------------------
        f32x4 acc[2][4];
        #pragma unroll
        for (int ntl = 0; ntl < 2; ++ntl)
            #pragma unroll
            for (int mt = 0; mt < 4; ++mt) acc[ntl][mt] = z4;
        #pragma unroll 2
        for (int ks = 0; ks < 10; ++ks) {
            bf16x8 a[4];
            #pragma unroll
            for (int mt = 0; mt < 4; ++mt)
                a[mt] = *(const bf16x8*)&afrag[((ks * 4 + mt) * 64 + lane) * 8];
            #pragma unroll
            for (int ntl = 0; ntl < 2; ++ntl) {
                int ntg = wave * 4 + nh * 2 + ntl;
                bf16x8 w = *(const bf16x8*)&Wb[((ks * 32 + ntg) * 64 + lane) * 8];
                #pragma unroll
                for (int mt = 0; mt < 4; ++mt)
                    acc[ntl][mt] = mfma16(w, a[mt], acc[ntl][mt]);         // A=W, B=x
            }
        }

        // ---- silu*gate -> h-fragment (B-operand) -> out-proj MFMA ----------
        // lane (q,c) holds h[hid = ntg*16 + q*4 + r][edge = mt*16 + c];
        // bf16x8 element j = ntl*4 + r matches Ob's permuted k-mapping.
        bf16x8 obf = *(const bf16x8*)&Ob[(((wave << 1) | nh) * 64 + lane) * 8];
        #pragma unroll
        for (int mt = 0; mt < 4; ++mt) {
            uint4 hq;
            hq.x = pk2(silu(acc[0][mt][0]) * bflo(gp[0][mt][0]),
                       silu(acc[0][mt][1]) * bfhi(gp[0][mt][0]));
            hq.y = pk2(silu(acc[0][mt][2]) * bflo(gp[0][mt][1]),
                       silu(acc[0][mt][3]) * bfhi(gp[0][mt][1]));
            hq.z = pk2(silu(acc[1][mt][0]) * bflo(gp[1][mt][0]),
                       silu(acc[1][mt][1]) * bfhi(gp[1][mt][0]));
            hq.w = pk2(silu(acc[1][mt][2]) * bflo(gp[1][mt][1]),
                       silu(acc[1][mt][3]) * bfhi(gp[1][mt][1]));
            oacc[mt] = mfma16(obf, *(bf16x8*)&hq, oacc[mt]);
        }
    }
    __syncthreads();   // all afrag reads complete; smem becomes red

    // ---- write per-wave out-proj partials ---------------------------------
    #pragma unroll
    for (int mt = 0; mt < 4; ++mt)
        *(f32x4*)&redf[((wave * 4 + mt) * 64 + lane) * 4] = oacc[mt];
    __syncthreads();

    // ---- final 8-way reduce + write ---------------------------------------
    {
        int head = t >> 6, el = t & 63;          // 8 heads x 64 edges
        int mt = el >> 4, c = el & 15;
        int l  = (head >> 2) * 16 + c;           // quad = head>>2
        int r  = head & 3;
        float s = 0.f;
        #pragma unroll
        for (int w = 0; w < 8; ++w)
            s += redf[((w * 4 + mt) * 64 + l) * 4 + r];
        int eg = e0 + el;
        if (eg < E) out[head * E + eg] = s + b_out[head];
    }
}

extern "C" void kernel_launch(void* const* d_in, const int* in_sizes, int n_in,
                              void* d_out, int out_size, void* d_ws, size_t ws_size,
                              hipStream_t stream) {
    const int*   anum        = (const int*)d_in[0];
    const int*   edge_index  = (const int*)d_in[1];
    const int*   edge_to_src = (const int*)d_in[2];
    const float* dist        = (const float*)d_in[3];
    const float* emb_table   = (const float*)d_in[4];
    const float* gate_W      = (const float*)d_in[5];
    const float* W_in        = (const float*)d_in[6];
    const float* b_in        = (const float*)d_in[7];
    const float* W_out       = (const float*)d_in[8];
    const float* b_out       = (const float*)d_in[9];
    const int E   = in_sizes[3];
    const int TBL = in_sizes[4];               // NELEM^2 * EMBED elements

    u16* Wb = (u16*)d_ws;
    u16* Gb = Wb + WB_ELEMS;
    u16* Ob = Gb + GB_ELEMS;
    u16* Eb = Ob + OB_ELEMS;

    const size_t need_bf16 = (size_t)(WB_ELEMS + GB_ELEMS + OB_ELEMS + TBL) * sizeof(u16);
    const bool use_bf16_table = ws_size >= need_bf16;

    int total = WB_ELEMS + GB_ELEMS + OB_ELEMS;
    prep_kernel<<<(total + 255) / 256, 256, 0, stream>>>(
        W_in, gate_W, W_out, b_in, Wb, Gb, Ob);

    const int nblocks = (E + M - 1) / M;
    if (use_bf16_table) {
        int npairs = TBL / 2;
        conv_table_kernel<<<(npairs + 255) / 256, 256, 0, stream>>>(
            emb_table, (uint*)Eb, npairs);
        pair_embed_kernel<true><<<nblocks, THREADS, 0, stream>>>(
            anum, edge_index, edge_to_src, dist, emb_table, Eb,
            b_out, Wb, Gb, Ob, (float*)d_out, E);
    } else {
        pair_embed_kernel<false><<<nblocks, THREADS, 0, stream>>>(
            anum, edge_index, edge_to_src, dist, emb_table, Eb,
            b_out, Wb, Gb, Ob, (float*)d_out, E);
    }
}

// Round 11
// 280.803 us; speedup vs baseline: 2.3018x; 1.1112x over previous
//
#include <hip/hip_runtime.h>
#include <hip/hip_bf16.h>

typedef unsigned short u16;
typedef unsigned int   uint;
typedef __attribute__((ext_vector_type(8))) short bf16x8;
typedef __attribute__((ext_vector_type(4))) float f32x4;

constexpr int NELEM = 100;
constexpr int EMBED = 256;
constexpr int HID   = 512;
constexpr int KX    = 306;     // EMBED + 50
constexpr int G     = 50;
constexpr int M     = 64;      // edges per block
constexpr int THREADS = 512;   // 8 waves

// frag-ready weight buffers in d_ws (bf16):
//  Wb : [10 ks][32 nt][64 lane][8]   (k==306 row carries b_in; >306 zero)
//  Gb : [ 2 ks][32 nt][64 lane][8]   (g>=50 zero)
//  Ob : [16 slice][64 lane][8]       permuted W_out for in-register out-proj:
//        slice s covers hid block s*32; element (lane,j) = W_out[lane&15]
//        [s*32 + (j>>2)*16 + (lane>>4)*4 + (j&3)]  (0 for lane&15 >= 8)
//  Eb : emb_table converted to bf16 (optional, if ws fits)
constexpr int WB_ELEMS = 10 * 32 * 64 * 8;
constexpr int GB_ELEMS = 2 * 32 * 64 * 8;
constexpr int OB_ELEMS = 16 * 64 * 8;

__device__ __forceinline__ u16 f2bf(float x) {
    uint u = __float_as_uint(x);
    u = (u + 0x7fffu + ((u >> 16) & 1u)) >> 16;
    return (u16)u;
}
// packed f32x2 -> bf16x2 (RNE); lowers to v_cvt_pk_bf16_f32 where available
__device__ __forceinline__ uint pk2(float a, float b) {
    __hip_bfloat162 h = __float22bfloat162_rn(make_float2(a, b));
    return *reinterpret_cast<uint*>(&h);
}
__device__ __forceinline__ float bflo(uint u) { return __uint_as_float(u << 16); }
__device__ __forceinline__ float bfhi(uint u) { return __uint_as_float(u & 0xffff0000u); }
// silu via raw v_rcp_f32 (1 ulp) instead of IEEE divide (~10 VALU ops)
__device__ __forceinline__ float silu(float p) {
    return p * __builtin_amdgcn_rcpf(1.f + __expf(-p));
}
__device__ __forceinline__ f32x4 mfma16(bf16x8 a, bf16x8 b, f32x4 c) {
    return __builtin_amdgcn_mfma_f32_16x16x32_bf16(a, b, c, 0, 0, 0);
}
__device__ __forceinline__ void load_lds16(const u16* g, u16* l) {
    __builtin_amdgcn_global_load_lds(
        (const __attribute__((address_space(1))) uint*)g,
        (__attribute__((address_space(3))) uint*)l, 16, 0, 0);
}

// ---- prep: weights -> fragment-ready bf16 layouts --------------------------
__global__ void prep_kernel(const float* __restrict__ W_in,   // [512][306]
                            const float* __restrict__ gate_W, // [512][50]
                            const float* __restrict__ W_out,  // [8][512]
                            const float* __restrict__ b_in,   // [512]
                            u16* __restrict__ Wb,
                            u16* __restrict__ Gb,
                            u16* __restrict__ Ob) {
    int idx = blockIdx.x * 256 + threadIdx.x;
    if (idx < WB_ELEMS) {
        int j = idx & 7, lane = (idx >> 3) & 63, nt = (idx >> 9) & 31, ks = idx >> 14;
        int h = nt * 16 + (lane & 15);
        int k = ks * 32 + (lane >> 4) * 8 + j;
        float v = (k < KX) ? W_in[h * KX + k] : ((k == KX) ? b_in[h] : 0.f);
        Wb[idx] = f2bf(v);
    } else if (idx < WB_ELEMS + GB_ELEMS) {
        int i2 = idx - WB_ELEMS;
        int j = i2 & 7, lane = (i2 >> 3) & 63, nt = (i2 >> 9) & 31, ks = i2 >> 14;
        int h = nt * 16 + (lane & 15);
        int g = ks * 32 + (lane >> 4) * 8 + j;
        Gb[i2] = f2bf((g < G) ? gate_W[h * G + g] : 0.f);
    } else if (idx < WB_ELEMS + GB_ELEMS + OB_ELEMS) {
        int i2 = idx - WB_ELEMS - GB_ELEMS;
        int j = i2 & 7, lane = (i2 >> 3) & 63, s = i2 >> 9;
        int m = lane & 15, q = lane >> 4;
        int hid = s * 32 + (j >> 2) * 16 + q * 4 + (j & 3);
        Ob[i2] = f2bf((m < 8) ? W_out[m * HID + hid] : 0.f);
    }
}

// ---- prep: emb_table f32 -> bf16 ------------------------------------------
__global__ void conv_table_kernel(const float* __restrict__ src,
                                  uint* __restrict__ dst, int npairs) {
    int i = blockIdx.x * 256 + threadIdx.x;
    if (i < npairs) {
        float2 v = ((const float2*)src)[i];
        dst[i] = pk2(v.x, v.y);
    }
}

// ---- fused main kernel -----------------------------------------------------
template <bool BF16_TABLE>
__global__ __launch_bounds__(THREADS, 4)
void pair_embed_kernel(const int* __restrict__ anum,
                       const int* __restrict__ edge_index,
                       const int* __restrict__ edge_to_src,
                       const float* __restrict__ dist,
                       const float* __restrict__ emb_table,
                       const u16* __restrict__ Eb,
                       const float* __restrict__ b_out,
                       const u16* __restrict__ Wb,
                       const u16* __restrict__ Gb,
                       const u16* __restrict__ Ob,
                       float* __restrict__ out,
                       int E) {
    // afrag [10 ks][4 mt][64 lane][8] = 40 KB; red (32 KB) unions into it.
    __shared__ __align__(16) u16 smem[10 * 4 * 64 * 8];
    __shared__ int   rowbase[M];
    __shared__ float dste[M];
    u16*   afrag = smem;
    float* redf  = (float*)smem;     // [8 wave][4 mt][64 lane][4]

    const int t  = threadIdx.x;
    const int e0 = blockIdx.x * M;
    const int wave = t >> 6, lane = t & 63;
    const int col = lane & 15, quad = lane >> 4;

    if (t < M) {
        int eg = e0 + t;
        int pair = 0; float d = 0.f;
        if (eg < E) {
            int src = edge_to_src[eg];
            pair = anum[edge_index[src]] + NELEM * anum[edge_index[E + src]];
            d = dist[eg];
        }
        rowbase[t] = pair * EMBED;
        dste[t]    = d;
    }
    __syncthreads();

    // ---- stage A-tile -----------------------------------------------------
    // emb chunks: wave w handles ks=w (k = w*32), mt 0..3. Lane (q,c) loads
    // 16B at row (mt*16+c), k-offset q*8. LDS dest = chunk base + lane*16B.
    {
        if (BF16_TABLE) {
            #pragma unroll
            for (int mt = 0; mt < 4; ++mt) {
                int rb = rowbase[mt * 16 + col];
                const u16* g = Eb + rb + wave * 32 + quad * 8;
                load_lds16(g, &afrag[((wave * 4 + mt) * 64 + lane) * 8]);
            }
        } else {
            #pragma unroll 1
            for (int mt = 0; mt < 4; ++mt) {
                int rb = rowbase[mt * 16 + col];
                const float4* src = (const float4*)(emb_table + rb + wave * 32 + quad * 8);
                float4 v0 = src[0], v1 = src[1];
                uint4 w;
                w.x = pk2(v0.x, v0.y); w.y = pk2(v0.z, v0.w);
                w.z = pk2(v1.x, v1.y); w.w = pk2(v1.z, v1.w);
                *(uint4*)&afrag[((wave * 4 + mt) * 64 + lane) * 8] = w;
            }
        }
        // rbf + bias chunk: one per wave: ks = 8+(wave&1), mt = wave>>1
        {
            const float sp    = 12.0f / 49.0f;
            const float coeff = -0.5f / (sp * sp);
            int ksr = 8 + (wave & 1), mtr = wave >> 1;
            float d  = dste[mtr * 16 + col];
            int   k0 = ksr * 32 + quad * 8;
            float f[8];
            #pragma unroll
            for (int j = 0; j < 8; ++j) {
                int k = k0 + j;
                int g = k - EMBED;
                float dd = d - sp * (float)g;
                f[j] = (g < G) ? __expf(coeff * dd * dd) : ((k == KX) ? 1.f : 0.f);
            }
            uint4 w;
            w.x = pk2(f[0], f[1]); w.y = pk2(f[2], f[3]);
            w.z = pk2(f[4], f[5]); w.w = pk2(f[6], f[7]);
            *(uint4*)&afrag[((ksr * 4 + mtr) * 64 + lane) * 8] = w;
        }
    }
    __syncthreads();

    const f32x4 z4 = {0.f, 0.f, 0.f, 0.f};
    f32x4 oacc[4] = {z4, z4, z4, z4};        // out-proj partials, D[head][edge]

    #pragma unroll
    for (int nh = 0; nh < 2; ++nh) {
        // ---- gate GEMM (ks 8..9), pack to bf16 (gp: 16 VGPR) ---------------
        uint gp[2][4][2];
        {
            f32x4 gacc[2][4];
            #pragma unroll
            for (int ntl = 0; ntl < 2; ++ntl)
                #pragma unroll
                for (int mt = 0; mt < 4; ++mt) gacc[ntl][mt] = z4;
            #pragma unroll
            for (int ks = 0; ks < 2; ++ks) {
                bf16x8 a[4];
                #pragma unroll
                for (int mt = 0; mt < 4; ++mt)
                    a[mt] = *(const bf16x8*)&afrag[(((8 + ks) * 4 + mt) * 64 + lane) * 8];
                #pragma unroll
                for (int ntl = 0; ntl < 2; ++ntl) {
                    int ntg = wave * 4 + nh * 2 + ntl;
                    bf16x8 g = *(const bf16x8*)&Gb[((ks * 32 + ntg) * 64 + lane) * 8];
                    #pragma unroll
                    for (int mt = 0; mt < 4; ++mt)
                        gacc[ntl][mt] = mfma16(g, a[mt], gacc[ntl][mt]);   // A=W, B=x
                }
            }
            #pragma unroll
            for (int ntl = 0; ntl < 2; ++ntl)
                #pragma unroll
                for (int mt = 0; mt < 4; ++mt) {
                    gp[ntl][mt][0] = pk2(gacc[ntl][mt][0], gacc[ntl][mt][1]);
                    gp[ntl][mt][1] = pk2(gacc[ntl][mt][2], gacc[ntl][mt][3]);
                }
        }

        // ---- main GEMM (ks 0..9, bias folded at k=306) ---------------------
        f32x4 acc[2][4];
        #pragma unroll
        for (int ntl = 0; ntl < 2; ++ntl)
            #pragma unroll
            for (int mt = 0; mt < 4; ++mt) acc[ntl][mt] = z4;
        #pragma unroll 2
        for (int ks = 0; ks < 10; ++ks) {
            bf16x8 a[4];
            #pragma unroll
            for (int mt = 0; mt < 4; ++mt)
                a[mt] = *(const bf16x8*)&afrag[((ks * 4 + mt) * 64 + lane) * 8];
            #pragma unroll
            for (int ntl = 0; ntl < 2; ++ntl) {
                int ntg = wave * 4 + nh * 2 + ntl;
                bf16x8 w = *(const bf16x8*)&Wb[((ks * 32 + ntg) * 64 + lane) * 8];
                #pragma unroll
                for (int mt = 0; mt < 4; ++mt)
                    acc[ntl][mt] = mfma16(w, a[mt], acc[ntl][mt]);         // A=W, B=x
            }
        }

        // ---- silu*gate -> h-fragment (B-operand) -> out-proj MFMA ----------
        // lane (q,c) holds h[hid = ntg*16 + q*4 + r][edge = mt*16 + c];
        // bf16x8 element j = ntl*4 + r matches Ob's permuted k-mapping.
        bf16x8 obf = *(const bf16x8*)&Ob[(((wave << 1) | nh) * 64 + lane) * 8];
        #pragma unroll
        for (int mt = 0; mt < 4; ++mt) {
            uint4 hq;
            hq.x = pk2(silu(acc[0][mt][0]) * bflo(gp[0][mt][0]),
                       silu(acc[0][mt][1]) * bfhi(gp[0][mt][0]));
            hq.y = pk2(silu(acc[0][mt][2]) * bflo(gp[0][mt][1]),
                       silu(acc[0][mt][3]) * bfhi(gp[0][mt][1]));
            hq.z = pk2(silu(acc[1][mt][0]) * bflo(gp[1][mt][0]),
                       silu(acc[1][mt][1]) * bfhi(gp[1][mt][0]));
            hq.w = pk2(silu(acc[1][mt][2]) * bflo(gp[1][mt][1]),
                       silu(acc[1][mt][3]) * bfhi(gp[1][mt][1]));
            oacc[mt] = mfma16(obf, *(bf16x8*)&hq, oacc[mt]);
        }
    }
    __syncthreads();   // all afrag reads complete; smem becomes red

    // ---- write per-wave out-proj partials ---------------------------------
    #pragma unroll
    for (int mt = 0; mt < 4; ++mt)
        *(f32x4*)&redf[((wave * 4 + mt) * 64 + lane) * 4] = oacc[mt];
    __syncthreads();

    // ---- final 8-way reduce + write ---------------------------------------
    {
        int head = t >> 6, el = t & 63;          // 8 heads x 64 edges
        int mt = el >> 4, c = el & 15;
        int l  = (head >> 2) * 16 + c;           // quad = head>>2
        int r  = head & 3;
        float s = 0.f;
        #pragma unroll
        for (int w = 0; w < 8; ++w)
            s += redf[((w * 4 + mt) * 64 + l) * 4 + r];
        int eg = e0 + el;
        if (eg < E) out[head * E + eg] = s + b_out[head];
    }
}

extern "C" void kernel_launch(void* const* d_in, const int* in_sizes, int n_in,
                              void* d_out, int out_size, void* d_ws, size_t ws_size,
                              hipStream_t stream) {
    const int*   anum        = (const int*)d_in[0];
    const int*   edge_index  = (const int*)d_in[1];
    const int*   edge_to_src = (const int*)d_in[2];
    const float* dist        = (const float*)d_in[3];
    const float* emb_table   = (const float*)d_in[4];
    const float* gate_W      = (const float*)d_in[5];
    const float* W_in        = (const float*)d_in[6];
    const float* b_in        = (const float*)d_in[7];
    const float* W_out       = (const float*)d_in[8];
    const float* b_out       = (const float*)d_in[9];
    const int E   = in_sizes[3];
    const int TBL = in_sizes[4];               // NELEM^2 * EMBED elements

    u16* Wb = (u16*)d_ws;
    u16* Gb = Wb + WB_ELEMS;
    u16* Ob = Gb + GB_ELEMS;
    u16* Eb = Ob + OB_ELEMS;

    const size_t need_bf16 = (size_t)(WB_ELEMS + GB_ELEMS + OB_ELEMS + TBL) * sizeof(u16);
    const bool use_bf16_table = ws_size >= need_bf16;

    int total = WB_ELEMS + GB_ELEMS + OB_ELEMS;
    prep_kernel<<<(total + 255) / 256, 256, 0, stream>>>(
        W_in, gate_W, W_out, b_in, Wb, Gb, Ob);

    const int nblocks = (E + M - 1) / M;
    if (use_bf16_table) {
        int npairs = TBL / 2;
        conv_table_kernel<<<(npairs + 255) / 256, 256, 0, stream>>>(
            emb_table, (uint*)Eb, npairs);
        pair_embed_kernel<true><<<nblocks, THREADS, 0, stream>>>(
            anum, edge_index, edge_to_src, dist, emb_table, Eb,
            b_out, Wb, Gb, Ob, (float*)d_out, E);
    } else {
        pair_embed_kernel<false><<<nblocks, THREADS, 0, stream>>>(
            anum, edge_index, edge_to_src, dist, emb_table, Eb,
            b_out, Wb, Gb, Ob, (float*)d_out, E);
    }
}

// Round 12
// 270.476 us; speedup vs baseline: 2.3897x; 1.0382x over previous
//
#include <hip/hip_runtime.h>
#include <hip/hip_bf16.h>

typedef unsigned short u16;
typedef unsigned int   uint;
typedef __attribute__((ext_vector_type(8))) short bf16x8;
typedef __attribute__((ext_vector_type(4))) float f32x4;

constexpr int NELEM = 100;
constexpr int EMBED = 256;
constexpr int HID   = 512;
constexpr int KX    = 306;     // EMBED + 50
constexpr int G     = 50;
constexpr int M     = 64;      // edges per block
constexpr int THREADS = 512;   // 8 waves

// frag-ready weight buffers in d_ws (bf16):
//  Wb : [32 nt][10 ks][64 lane][8]   per-wave ks-stream contiguous (1 KB steps)
//        (k==306 row carries b_in; >306 zero)
//  Gb : [32 nt][ 2 ks][64 lane][8]   (g>=50 zero)
//  Ob : [16 slice][64 lane][8]       permuted W_out for in-register out-proj:
//        slice s covers hid block s*32; element (lane,j) = W_out[lane&15]
//        [s*32 + (j>>2)*16 + (lane>>4)*4 + (j&3)]  (0 for lane&15 >= 8)
//  Eb : emb_table converted to bf16 (optional, if ws fits)
constexpr int WB_ELEMS = 32 * 10 * 64 * 8;
constexpr int GB_ELEMS = 32 * 2 * 64 * 8;
constexpr int OB_ELEMS = 16 * 64 * 8;
constexpr int WEIGHT_ELEMS = WB_ELEMS + GB_ELEMS + OB_ELEMS;   // 204800

__device__ __forceinline__ u16 f2bf(float x) {
    uint u = __float_as_uint(x);
    u = (u + 0x7fffu + ((u >> 16) & 1u)) >> 16;
    return (u16)u;
}
// packed f32x2 -> bf16x2 (RNE)
__device__ __forceinline__ uint pk2(float a, float b) {
    __hip_bfloat162 h = __float22bfloat162_rn(make_float2(a, b));
    return *reinterpret_cast<uint*>(&h);
}
__device__ __forceinline__ float bflo(uint u) { return __uint_as_float(u << 16); }
__device__ __forceinline__ float bfhi(uint u) { return __uint_as_float(u & 0xffff0000u); }
// silu via raw v_rcp_f32 (1 ulp) instead of IEEE divide
__device__ __forceinline__ float silu(float p) {
    return p * __builtin_amdgcn_rcpf(1.f + __expf(-p));
}
__device__ __forceinline__ f32x4 mfma16(bf16x8 a, bf16x8 b, f32x4 c) {
    return __builtin_amdgcn_mfma_f32_16x16x32_bf16(a, b, c, 0, 0, 0);
}
__device__ __forceinline__ void load_lds16(const u16* g, u16* l) {
    __builtin_amdgcn_global_load_lds(
        (const __attribute__((address_space(1))) uint*)g,
        (__attribute__((address_space(3))) uint*)l, 16, 0, 0);
}

// ---- prep: weights -> frag layouts, plus emb_table f32->bf16 (fused) -------
__global__ void prep_all_kernel(const float* __restrict__ W_in,   // [512][306]
                                const float* __restrict__ gate_W, // [512][50]
                                const float* __restrict__ W_out,  // [8][512]
                                const float* __restrict__ b_in,   // [512]
                                const float* __restrict__ table,  // emb f32
                                u16* __restrict__ Wb,
                                u16* __restrict__ Gb,
                                u16* __restrict__ Ob,
                                uint* __restrict__ Eb4,           // bf16 table
                                int nconv, int do_conv) {
    int idx = blockIdx.x * 256 + threadIdx.x;
    if (idx < WB_ELEMS) {
        int j = idx & 7, lane = (idx >> 3) & 63, kn = idx >> 9;
        int ks = kn % 10, nt = kn / 10;
        int h = nt * 16 + (lane & 15);
        int k = ks * 32 + (lane >> 4) * 8 + j;
        float v = (k < KX) ? W_in[h * KX + k] : ((k == KX) ? b_in[h] : 0.f);
        Wb[idx] = f2bf(v);
    } else if (idx < WB_ELEMS + GB_ELEMS) {
        int i2 = idx - WB_ELEMS;
        int j = i2 & 7, lane = (i2 >> 3) & 63, kn = i2 >> 9;
        int ks = kn & 1, nt = kn >> 1;
        int h = nt * 16 + (lane & 15);
        int g = ks * 32 + (lane >> 4) * 8 + j;
        Gb[i2] = f2bf((g < G) ? gate_W[h * G + g] : 0.f);
    } else if (idx < WEIGHT_ELEMS) {
        int i2 = idx - WB_ELEMS - GB_ELEMS;
        int j = i2 & 7, lane = (i2 >> 3) & 63, s = i2 >> 9;
        int m = lane & 15, q = lane >> 4;
        int hid = s * 32 + (j >> 2) * 16 + q * 4 + (j & 3);
        Ob[i2] = f2bf((m < 8) ? W_out[m * HID + hid] : 0.f);
    } else if (do_conv) {
        int i = idx - WEIGHT_ELEMS;          // one thread = 8 floats -> uint4
        if (i < nconv) {
            const float4* s4 = (const float4*)(table + i * 8);
            float4 v0 = s4[0], v1 = s4[1];
            uint4 w;
            w.x = pk2(v0.x, v0.y); w.y = pk2(v0.z, v0.w);
            w.z = pk2(v1.x, v1.y); w.w = pk2(v1.z, v1.w);
            ((uint4*)Eb4)[i] = w;
        }
    }
}

// ---- fused main kernel -----------------------------------------------------
template <bool BF16_TABLE>
__global__ __launch_bounds__(THREADS, 4)
void pair_embed_kernel(const int* __restrict__ anum,
                       const int* __restrict__ edge_index,
                       const int* __restrict__ edge_to_src,
                       const float* __restrict__ dist,
                       const float* __restrict__ emb_table,
                       const u16* __restrict__ Eb,
                       const float* __restrict__ b_out,
                       const u16* __restrict__ Wb,
                       const u16* __restrict__ Gb,
                       const u16* __restrict__ Ob,
                       float* __restrict__ out,
                       int E) {
    // afrag [10 ks][4 mt][64 lane][8] = 40 KB; red (32 KB) unions into it.
    __shared__ __align__(16) u16 smem[10 * 4 * 64 * 8];
    __shared__ int   rowbase[M];
    __shared__ float dste[M];
    u16*   afrag = smem;
    float* redf  = (float*)smem;     // [8 wave][4 mt][64 lane][4]

    const int t  = threadIdx.x;
    const int e0 = blockIdx.x * M;
    const int wave = t >> 6, lane = t & 63;
    const int col = lane & 15, quad = lane >> 4;

    if (t < M) {
        int eg = e0 + t;
        int pair = 0; float d = 0.f;
        if (eg < E) {
            int src = edge_to_src[eg];
            pair = anum[edge_index[src]] + NELEM * anum[edge_index[E + src]];
            d = dist[eg];
        }
        rowbase[t] = pair * EMBED;
        dste[t]    = d;
    }
    __syncthreads();

    // ---- stage A-tile -----------------------------------------------------
    // emb chunks: wave w handles ks=w (k = w*32), mt 0..3. Lane (q,c) loads
    // 16B at row (mt*16+c), k-offset q*8. LDS dest = chunk base + lane*16B.
    {
        if (BF16_TABLE) {
            #pragma unroll
            for (int mt = 0; mt < 4; ++mt) {
                int rb = rowbase[mt * 16 + col];
                const u16* g = Eb + rb + wave * 32 + quad * 8;
                load_lds16(g, &afrag[((wave * 4 + mt) * 64 + lane) * 8]);
            }
        } else {
            #pragma unroll 1
            for (int mt = 0; mt < 4; ++mt) {
                int rb = rowbase[mt * 16 + col];
                const float4* src = (const float4*)(emb_table + rb + wave * 32 + quad * 8);
                float4 v0 = src[0], v1 = src[1];
                uint4 w;
                w.x = pk2(v0.x, v0.y); w.y = pk2(v0.z, v0.w);
                w.z = pk2(v1.x, v1.y); w.w = pk2(v1.z, v1.w);
                *(uint4*)&afrag[((wave * 4 + mt) * 64 + lane) * 8] = w;
            }
        }
        // rbf + bias chunk: one per wave: ks = 8+(wave&1), mt = wave>>1
        {
            const float sp    = 12.0f / 49.0f;
            const float coeff = -0.5f / (sp * sp);
            int ksr = 8 + (wave & 1), mtr = wave >> 1;
            float d  = dste[mtr * 16 + col];
            int   k0 = ksr * 32 + quad * 8;
            float f[8];
            #pragma unroll
            for (int j = 0; j < 8; ++j) {
                int k = k0 + j;
                int g = k - EMBED;
                float dd = d - sp * (float)g;
                f[j] = (g < G) ? __expf(coeff * dd * dd) : ((k == KX) ? 1.f : 0.f);
            }
            uint4 w;
            w.x = pk2(f[0], f[1]); w.y = pk2(f[2], f[3]);
            w.z = pk2(f[4], f[5]); w.w = pk2(f[6], f[7]);
            *(uint4*)&afrag[((ksr * 4 + mtr) * 64 + lane) * 8] = w;
        }
    }
    __syncthreads();

    const f32x4 z4 = {0.f, 0.f, 0.f, 0.f};
    f32x4 oacc[4] = {z4, z4, z4, z4};        // out-proj partials, D[head][edge]

    #pragma unroll
    for (int nh = 0; nh < 2; ++nh) {
        // ---- gate GEMM (ks 8..9), pack to bf16 (gp: 16 VGPR) ---------------
        uint gp[2][4][2];
        {
            f32x4 gacc[2][4];
            #pragma unroll
            for (int ntl = 0; ntl < 2; ++ntl)
                #pragma unroll
                for (int mt = 0; mt < 4; ++mt) gacc[ntl][mt] = z4;
            #pragma unroll
            for (int ks = 0; ks < 2; ++ks) {
                bf16x8 a[4];
                #pragma unroll
                for (int mt = 0; mt < 4; ++mt)
                    a[mt] = *(const bf16x8*)&afrag[(((8 + ks) * 4 + mt) * 64 + lane) * 8];
                #pragma unroll
                for (int ntl = 0; ntl < 2; ++ntl) {
                    int ntg = wave * 4 + nh * 2 + ntl;
                    bf16x8 g = *(const bf16x8*)&Gb[((ntg * 2 + ks) * 64 + lane) * 8];
                    #pragma unroll
                    for (int mt = 0; mt < 4; ++mt)
                        gacc[ntl][mt] = mfma16(g, a[mt], gacc[ntl][mt]);   // A=W, B=x
                }
            }
            #pragma unroll
            for (int ntl = 0; ntl < 2; ++ntl)
                #pragma unroll
                for (int mt = 0; mt < 4; ++mt) {
                    gp[ntl][mt][0] = pk2(gacc[ntl][mt][0], gacc[ntl][mt][1]);
                    gp[ntl][mt][1] = pk2(gacc[ntl][mt][2], gacc[ntl][mt][3]);
                }
        }

        // ---- main GEMM (ks 0..9, bias folded at k=306) ---------------------
        // Wb stream for this wave's ntg: 10 contiguous 1-KB chunks.
        f32x4 acc[2][4];
        #pragma unroll
        for (int ntl = 0; ntl < 2; ++ntl)
            #pragma unroll
            for (int mt = 0; mt < 4; ++mt) acc[ntl][mt] = z4;
        const u16* wb0 = &Wb[(((wave * 4 + nh * 2 + 0) * 10) * 64 + lane) * 8];
        const u16* wb1 = &Wb[(((wave * 4 + nh * 2 + 1) * 10) * 64 + lane) * 8];
        #pragma unroll 2
        for (int ks = 0; ks < 10; ++ks) {
            bf16x8 a[4];
            #pragma unroll
            for (int mt = 0; mt < 4; ++mt)
                a[mt] = *(const bf16x8*)&afrag[((ks * 4 + mt) * 64 + lane) * 8];
            bf16x8 w0 = *(const bf16x8*)&wb0[ks * 512];
            #pragma unroll
            for (int mt = 0; mt < 4; ++mt)
                acc[0][mt] = mfma16(w0, a[mt], acc[0][mt]);                // A=W, B=x
            bf16x8 w1 = *(const bf16x8*)&wb1[ks * 512];
            #pragma unroll
            for (int mt = 0; mt < 4; ++mt)
                acc[1][mt] = mfma16(w1, a[mt], acc[1][mt]);
        }

        // ---- silu*gate -> h-fragment (B-operand) -> out-proj MFMA ----------
        // lane (q,c) holds h[hid = ntg*16 + q*4 + r][edge = mt*16 + c];
        // bf16x8 element j = ntl*4 + r matches Ob's permuted k-mapping.
        bf16x8 obf = *(const bf16x8*)&Ob[(((wave << 1) | nh) * 64 + lane) * 8];
        #pragma unroll
        for (int mt = 0; mt < 4; ++mt) {
            uint4 hq;
            hq.x = pk2(silu(acc[0][mt][0]) * bflo(gp[0][mt][0]),
                       silu(acc[0][mt][1]) * bfhi(gp[0][mt][0]));
            hq.y = pk2(silu(acc[0][mt][2]) * bflo(gp[0][mt][1]),
                       silu(acc[0][mt][3]) * bfhi(gp[0][mt][1]));
            hq.z = pk2(silu(acc[1][mt][0]) * bflo(gp[1][mt][0]),
                       silu(acc[1][mt][1]) * bfhi(gp[1][mt][0]));
            hq.w = pk2(silu(acc[1][mt][2]) * bflo(gp[1][mt][1]),
                       silu(acc[1][mt][3]) * bfhi(gp[1][mt][1]));
            oacc[mt] = mfma16(obf, *(bf16x8*)&hq, oacc[mt]);
        }
    }
    __syncthreads();   // all afrag reads complete; smem becomes red

    // ---- write per-wave out-proj partials ---------------------------------
    #pragma unroll
    for (int mt = 0; mt < 4; ++mt)
        *(f32x4*)&redf[((wave * 4 + mt) * 64 + lane) * 4] = oacc[mt];
    __syncthreads();

    // ---- final 8-way reduce + write ---------------------------------------
    {
        int head = t >> 6, el = t & 63;          // 8 heads x 64 edges
        int mt = el >> 4, c = el & 15;
        int l  = (head >> 2) * 16 + c;           // quad = head>>2
        int r  = head & 3;
        float s = 0.f;
        #pragma unroll
        for (int w = 0; w < 8; ++w)
            s += redf[((w * 4 + mt) * 64 + l) * 4 + r];
        int eg = e0 + el;
        if (eg < E) out[head * E + eg] = s + b_out[head];
    }
}

extern "C" void kernel_launch(void* const* d_in, const int* in_sizes, int n_in,
                              void* d_out, int out_size, void* d_ws, size_t ws_size,
                              hipStream_t stream) {
    const int*   anum        = (const int*)d_in[0];
    const int*   edge_index  = (const int*)d_in[1];
    const int*   edge_to_src = (const int*)d_in[2];
    const float* dist        = (const float*)d_in[3];
    const float* emb_table   = (const float*)d_in[4];
    const float* gate_W      = (const float*)d_in[5];
    const float* W_in        = (const float*)d_in[6];
    const float* b_in        = (const float*)d_in[7];
    const float* W_out       = (const float*)d_in[8];
    const float* b_out       = (const float*)d_in[9];
    const int E   = in_sizes[3];
    const int TBL = in_sizes[4];               // NELEM^2 * EMBED elements

    u16* Wb = (u16*)d_ws;
    u16* Gb = Wb + WB_ELEMS;
    u16* Ob = Gb + GB_ELEMS;
    u16* Eb = Ob + OB_ELEMS;

    const size_t need_bf16 = (size_t)(WEIGHT_ELEMS + TBL) * sizeof(u16);
    const bool use_bf16_table = ws_size >= need_bf16;

    const int nconv = TBL / 8;                 // 8 floats per conv thread
    const int total = WEIGHT_ELEMS + (use_bf16_table ? nconv : 0);
    prep_all_kernel<<<(total + 255) / 256, 256, 0, stream>>>(
        W_in, gate_W, W_out, b_in, emb_table,
        Wb, Gb, Ob, (uint*)Eb, nconv, use_bf16_table ? 1 : 0);

    const int nblocks = (E + M - 1) / M;
    if (use_bf16_table) {
        pair_embed_kernel<true><<<nblocks, THREADS, 0, stream>>>(
            anum, edge_index, edge_to_src, dist, emb_table, Eb,
            b_out, Wb, Gb, Ob, (float*)d_out, E);
    } else {
        pair_embed_kernel<false><<<nblocks, THREADS, 0, stream>>>(
            anum, edge_index, edge_to_src, dist, emb_table, Eb,
            b_out, Wb, Gb, Ob, (float*)d_out, E);
    }
}